// Round 2
// baseline (2430.200 us; speedup 1.0000x reference)
//
#include <hip/hip_runtime.h>
#include <hip/hip_bf16.h>

namespace {

constexpr int N    = 100000;
constexpr int M    = 12;
constexpr int ORIG = 92;
constexpr int NBR  = 41;
constexpr int F    = 64;   // atom feature dim
constexpr int H    = 128;  // head hidden
constexpr int N0   = 2000; // crystals
constexpr float EPS = 1e-5f;

constexpr int TI_STATS = 25;   // atoms per block in stats pass  (100000 % 25 == 0)
constexpr int TA_APPLY = 20;   // atoms per block in apply pass  (100000 % 20 == 0)
constexpr int NBLK_STATS = N / TI_STATS;  // 4000
constexpr int NBLK_APPLY = N / TA_APPLY;  // 5000

__device__ __forceinline__ float softplusf(float x){
  // jax.nn.softplus = max(x,0) + log1p(exp(-|x|))
  return fmaxf(x, 0.f) + log1pf(expf(-fabsf(x)));
}
__device__ __forceinline__ float sigmoidf(float x){
  return 1.f / (1.f + expf(-x));
}
__device__ __forceinline__ unsigned short f2bf(float f){
  __hip_bfloat16 h = __float2bfloat16(f);
  unsigned short u; __builtin_memcpy(&u, &h, 2); return u;
}
__device__ __forceinline__ float bf2f(unsigned short u){
  __hip_bfloat16 h; __builtin_memcpy(&h, &u, 2); return __bfloat162float(h);
}

// ---------------- embedding: a = atom_fea @ W_emb + b_emb ----------------
// block = 256 threads = 4 atoms x 64 cols; grid = 25000
__global__ void k_embed(const float* __restrict__ af, const float* __restrict__ W,
                        const float* __restrict__ b, float* __restrict__ a){
  __shared__ float row[4][ORIG];
  int base = blockIdx.x * 4;
  for(int t = threadIdx.x; t < 4*ORIG; t += 256){
    row[t/ORIG][t%ORIG] = af[(size_t)(base + t/ORIG)*ORIG + (t%ORIG)];
  }
  __syncthreads();
  int i = base + (threadIdx.x >> 6);
  int j = threadIdx.x & 63;
  const float* r = row[threadIdx.x >> 6];
  float acc = b[j];
  #pragma unroll
  for(int k = 0; k < ORIG; k++) acc = fmaf(r[k], W[k*F + j], acc);
  a[(size_t)i*F + j] = acc;
}

// ---------------- S = X@W[0:64,:] + bias ; P = X@W[64:128,:] (bf16 pairs) --
// block = 192: threads 0..127 -> S col t ; threads 128..191 -> P cols c,c+64
// grid = N
__global__ void k_spgemm(const float* __restrict__ X, const float* __restrict__ W,
                         const float* __restrict__ bias,
                         float* __restrict__ S, ushort2* __restrict__ P2){
  __shared__ float x[F];
  int i = blockIdx.x;
  int t = threadIdx.x;
  if(t < F) x[t] = X[(size_t)i*F + t];
  __syncthreads();
  if(t < 128){
    float acc = bias[t];
    #pragma unroll
    for(int k = 0; k < F; k++) acc = fmaf(x[k], W[k*128 + t], acc);
    S[(size_t)i*128 + t] = acc;
  } else {
    int c = t - 128;
    float alo = 0.f, ahi = 0.f;
    #pragma unroll
    for(int k = 0; k < F; k++){
      float xv = x[k];
      alo = fmaf(xv, W[(F + k)*128 + c], alo);
      ahi = fmaf(xv, W[(F + k)*128 + 64 + c], ahi);
    }
    ushort2 o; o.x = f2bf(alo); o.y = f2bf(ahi);
    P2[(size_t)i*64 + c] = o;
  }
}

// ---------------- stats pass: column sums & sumsq of gated ----------------
// block = 64 threads; thread j handles cols j and j+64. grid = N/TI_STATS.
// partial layout per block (256 floats): [sum(128) | sumsq(128)]
__global__ void k_stats(const float* __restrict__ S, const ushort2* __restrict__ P2,
                        const float* __restrict__ nbr, const int* __restrict__ idx,
                        const float* __restrict__ W, float* __restrict__ part){
  int j = threadIdx.x;
  float we_lo[NBR], we_hi[NBR];
  #pragma unroll
  for(int k = 0; k < NBR; k++){
    we_lo[k] = W[(128 + k)*128 + j];
    we_hi[k] = W[(128 + k)*128 + 64 + j];
  }
  __shared__ float nb[M*NBR];
  __shared__ int   ix[M];
  float s_lo = 0.f, ss_lo = 0.f, s_hi = 0.f, ss_hi = 0.f;
  int i0 = blockIdx.x * TI_STATS;
  for(int t = 0; t < TI_STATS; t++){
    int i = i0 + t;
    __syncthreads();
    for(int u = threadIdx.x; u < M*NBR; u += 64) nb[u] = nbr[(size_t)i*(M*NBR) + u];
    if(threadIdx.x < M) ix[threadIdx.x] = idx[i*M + threadIdx.x];
    __syncthreads();
    float Slo = S[(size_t)i*128 + j];
    float Shi = S[(size_t)i*128 + 64 + j];
    for(int m = 0; m < M; m++){
      int p = ix[m];
      ushort2 pv = P2[(size_t)p*64 + j];
      float glo = Slo + bf2f(pv.x);
      float ghi = Shi + bf2f(pv.y);
      #pragma unroll
      for(int k = 0; k < NBR; k++){
        float nv = nb[m*NBR + k];
        glo = fmaf(nv, we_lo[k], glo);
        ghi = fmaf(nv, we_hi[k], ghi);
      }
      s_lo += glo;  ss_lo = fmaf(glo, glo, ss_lo);
      s_hi += ghi;  ss_hi = fmaf(ghi, ghi, ss_hi);
    }
  }
  float* pb = part + (size_t)blockIdx.x * 256;
  pb[j]        = s_lo;
  pb[64 + j]   = s_hi;
  pb[128 + j]  = ss_lo;
  pb[192 + j]  = ss_hi;
}

// ---------------- generic column reduction of partials --------------------
// grid = width ; block = 256
__global__ void k_reduce(const float* __restrict__ part, int nblocks, int width,
                         float* __restrict__ out){
  int col = blockIdx.x;
  float s = 0.f;
  for(int b = threadIdx.x; b < nblocks; b += 256) s += part[(size_t)b*width + col];
  __shared__ float red[256];
  red[threadIdx.x] = s;
  __syncthreads();
  for(int off = 128; off; off >>= 1){
    if(threadIdx.x < off) red[threadIdx.x] += red[threadIdx.x + off];
    __syncthreads();
  }
  if(threadIdx.x == 0) out[col] = red[0];
}

// ---------------- BN finalize: scale/shift from reduced sums --------------
__global__ void k_finalize(const float* __restrict__ red, const float* __restrict__ gamma,
                           const float* __restrict__ beta, float* __restrict__ sc,
                           float* __restrict__ sh, float inv, int nch){
  int j = threadIdx.x;
  if(j < nch){
    float mu  = red[j] * inv;
    float var = fmaxf(red[nch + j] * inv - mu*mu, 0.f);
    float r   = rsqrtf(var + EPS);
    float s   = gamma[j] * r;
    sc[j] = s;
    sh[j] = beta[j] - mu * s;
  }
}

// ---------------- apply pass: BN1 + sigmoid*softplus, sum over m ----------
// block = 128: sub = tid>>6 (atom of pair), j = tid&63. grid = N/TA_APPLY.
// partial layout per block (128 floats): [sum(64) | sumsq(64)] of summed cols
__global__ void k_apply(const float* __restrict__ S, const ushort2* __restrict__ P2,
                        const float* __restrict__ nbr, const int* __restrict__ idx,
                        const float* __restrict__ W,
                        const float* __restrict__ sc1, const float* __restrict__ sh1,
                        float* __restrict__ SUMb, float* __restrict__ part){
  int j   = threadIdx.x & 63;
  int sub = threadIdx.x >> 6;
  float we_f[NBR], we_c[NBR];
  #pragma unroll
  for(int k = 0; k < NBR; k++){
    we_f[k] = W[(128 + k)*128 + j];
    we_c[k] = W[(128 + k)*128 + 64 + j];
  }
  float c1f = sc1[j], h1f = sh1[j];
  float c1c = sc1[64 + j], h1c = sh1[64 + j];
  __shared__ float nb[2*M*NBR];
  __shared__ int   ix[2*M];
  __shared__ float rs[2][64], rss[2][64];
  float sum_s = 0.f, sum_ss = 0.f;
  int i0 = blockIdx.x * TA_APPLY;
  for(int t = 0; t < TA_APPLY; t += 2){
    int ibase = i0 + t;
    int i = ibase + sub;
    __syncthreads();
    for(int u = threadIdx.x; u < 2*M*NBR; u += 128) nb[u] = nbr[(size_t)ibase*(M*NBR) + u];
    if(threadIdx.x < 2*M) ix[threadIdx.x] = idx[ibase*M + threadIdx.x];
    __syncthreads();
    float Sf = S[(size_t)i*128 + j];
    float Sc = S[(size_t)i*128 + 64 + j];
    float acc = 0.f;
    for(int m = 0; m < M; m++){
      int p = ix[sub*M + m];
      ushort2 pv = P2[(size_t)p*64 + j];
      float gf = Sf + bf2f(pv.x);
      float gc = Sc + bf2f(pv.y);
      #pragma unroll
      for(int k = 0; k < NBR; k++){
        float nv = nb[sub*M*NBR + m*NBR + k];
        gf = fmaf(nv, we_f[k], gf);
        gc = fmaf(nv, we_c[k], gc);
      }
      gf = fmaf(gf, c1f, h1f);
      gc = fmaf(gc, c1c, h1c);
      acc += sigmoidf(gf) * softplusf(gc);
    }
    SUMb[(size_t)i*64 + j] = acc;
    sum_s += acc;
    sum_ss = fmaf(acc, acc, sum_ss);
  }
  rs[sub][j]  = sum_s;
  rss[sub][j] = sum_ss;
  __syncthreads();
  if(threadIdx.x < 64){
    float* pb = part + (size_t)blockIdx.x * 128;
    pb[threadIdx.x]      = rs[0][threadIdx.x]  + rs[1][threadIdx.x];
    pb[64 + threadIdx.x] = rss[0][threadIdx.x] + rss[1][threadIdx.x];
  }
}

// ---------------- epilogue: Y = softplus(X + BN2(summed)) [+res] ----------
__global__ void k_epi(const float* __restrict__ X, const float* __restrict__ SUMb,
                      const float* __restrict__ sc2, const float* __restrict__ sh2,
                      float* __restrict__ Y, int res){
  int stride = gridDim.x * blockDim.x;
  for(int e = blockIdx.x * blockDim.x + threadIdx.x; e < N*F; e += stride){
    int j = e & 63;
    float x = X[e];
    float t = softplusf(x + fmaf(SUMb[e], sc2[j], sh2[j]));
    Y[e] = res ? softplusf(t + x) : t;
  }
}

// ---------------- segment-mean pool over sorted crystal_id ----------------
// grid = N0, block = 64
__global__ void k_pool(const float* __restrict__ A2, const int* __restrict__ cid,
                       float* __restrict__ POOL){
  int c = blockIdx.x;
  int j = threadIdx.x;
  int lo = 0, hi = N;
  while(lo < hi){ int mid = (lo + hi) >> 1; if(cid[mid] < c) lo = mid + 1; else hi = mid; }
  int s0 = lo;
  lo = s0; hi = N;
  while(lo < hi){ int mid = (lo + hi) >> 1; if(cid[mid] < c + 1) lo = mid + 1; else hi = mid; }
  int s1 = lo;
  float s = 0.f;
  for(int i = s0; i < s1; i++) s += A2[(size_t)i*F + j];
  POOL[c*F + j] = s / fmaxf((float)(s1 - s0), 1.f);
}

// ---------------- head: out = sp(sp(pool)@Wfc+bfc)@Wout + bout ------------
// grid = N0, block = 128
__global__ void k_head(const float* __restrict__ POOL, const float* __restrict__ Wfc,
                       const float* __restrict__ bfc, const float* __restrict__ Wout,
                       const float* __restrict__ bout, float* __restrict__ out){
  int c = blockIdx.x;
  int t = threadIdx.x;
  __shared__ float spv[F];
  if(t < F) spv[t] = softplusf(POOL[c*F + t]);
  __syncthreads();
  float h = bfc[t];
  #pragma unroll
  for(int k = 0; k < F; k++) h = fmaf(spv[k], Wfc[k*H + t], h);
  h = softplusf(h);
  float v = h * Wout[t];
  #pragma unroll
  for(int off = 32; off; off >>= 1) v += __shfl_down(v, off, 64);
  __shared__ float red[2];
  if((t & 63) == 0) red[t >> 6] = v;
  __syncthreads();
  if(t == 0) out[c] = red[0] + red[1] + bout[0];
}

} // namespace

extern "C" void kernel_launch(void* const* d_in, const int* in_sizes, int n_in,
                              void* d_out, int out_size, void* d_ws, size_t ws_size,
                              hipStream_t stream){
  const float* atom_fea = (const float*)d_in[0];
  const float* nbr_fea  = (const float*)d_in[1];
  const int*   nbr_idx  = (const int*)d_in[2];
  const int*   cid      = (const int*)d_in[3];
  const float* W_emb = (const float*)d_in[4];
  const float* b_emb = (const float*)d_in[5];
  const float* cW  = (const float*)d_in[6];
  const float* cb  = (const float*)d_in[7];
  const float* cg1 = (const float*)d_in[8];
  const float* cbt1= (const float*)d_in[9];
  const float* cg2 = (const float*)d_in[10];
  const float* cbt2= (const float*)d_in[11];
  const float* rW  = (const float*)d_in[12];
  const float* rb  = (const float*)d_in[13];
  const float* rg1 = (const float*)d_in[14];
  const float* rbt1= (const float*)d_in[15];
  const float* rg2 = (const float*)d_in[16];
  const float* rbt2= (const float*)d_in[17];
  const float* W_fc = (const float*)d_in[18];
  const float* b_fc = (const float*)d_in[19];
  const float* W_out= (const float*)d_in[20];
  const float* b_out= (const float*)d_in[21];
  float* out = (float*)d_out;

  char* ws = (char*)d_ws;
  // layout (bytes)
  float*   A0   = (float*)(ws + 0);            // N*64 f32  (a, later a2)
  float*   A1   = (float*)(ws + 25600000);     // N*64 f32  (a1)
  float*   SUMb = (float*)(ws + 51200000);     // N*64 f32  (summed)
  float*   S    = (float*)(ws + 76800000);     // N*128 f32 (self part + bias)
  ushort2* P2   = (ushort2*)(ws + 128000000);  // N*64 ushort2 (P cols j, j+64 bf16)
  float*   POOL = (float*)(ws + 153600000);    // 2000*64 f32
  float*   SP1  = (float*)(ws + 154112000);    // 4000*256 f32 stats partials
  float*   SP2  = (float*)(ws + 158208000);    // 5000*128 f32 apply partials
  float*   STAT = (float*)(ws + 160768000);    // 768 f32: [red1 256][red2 128][sc1 128][sh1 128][sc2 64][sh2 64]
  float* RED1 = STAT;         // 0..255
  float* RED2 = STAT + 256;   // 256..383
  float* SC1  = STAT + 384;
  float* SH1  = STAT + 512;
  float* SC2  = STAT + 640;
  float* SH2  = STAT + 704;

  // 1) embedding
  k_embed<<<N/4, 256, 0, stream>>>(atom_fea, W_emb, b_emb, A0);

  // 2) two conv layers
  for(int layer = 0; layer < 2; layer++){
    const float* W   = layer ? rW   : cW;
    const float* bb  = layer ? rb   : cb;
    const float* g1  = layer ? rg1  : cg1;
    const float* bt1 = layer ? rbt1 : cbt1;
    const float* g2  = layer ? rg2  : cg2;
    const float* bt2 = layer ? rbt2 : cbt2;
    const float* X = layer ? A1 : A0;
    float*       Y = layer ? A0 : A1;

    k_spgemm<<<N, 192, 0, stream>>>(X, W, bb, S, P2);
    k_stats<<<NBLK_STATS, 64, 0, stream>>>(S, P2, nbr_fea, nbr_idx, W, SP1);
    k_reduce<<<256, 256, 0, stream>>>(SP1, NBLK_STATS, 256, RED1);
    k_finalize<<<1, 128, 0, stream>>>(RED1, g1, bt1, SC1, SH1, 1.f/(float)(N*M), 128);
    k_apply<<<NBLK_APPLY, 128, 0, stream>>>(S, P2, nbr_fea, nbr_idx, W, SC1, SH1, SUMb, SP2);
    k_reduce<<<128, 256, 0, stream>>>(SP2, NBLK_APPLY, 128, RED2);
    k_finalize<<<1, 128, 0, stream>>>(RED2, g2, bt2, SC2, SH2, 1.f/(float)N, 64);
    k_epi<<<2048, 256, 0, stream>>>(X, SUMb, SC2, SH2, Y, layer);
  }

  // 3) per-crystal mean pool (a2 is in A0)
  k_pool<<<N0, 64, 0, stream>>>(A0, cid, POOL);

  // 4) head
  k_head<<<N0, 128, 0, stream>>>(POOL, W_fc, b_fc, W_out, b_out, out);
}

// Round 6
// 1754.283 us; speedup vs baseline: 1.3853x; 1.3853x over previous
//
#include <hip/hip_runtime.h>
#include <hip/hip_bf16.h>

namespace {

constexpr int N    = 100000;
constexpr int M    = 12;
constexpr int ORIG = 92;
constexpr int NBR  = 41;
constexpr int F    = 64;
constexpr int H    = 128;
constexpr int N0   = 2000;
constexpr float EPS = 1e-5f;

constexpr int ATB  = 16;        // atoms per block in pass kernels
constexpr int NBLK = N / ATB;   // 6250

typedef __attribute__((ext_vector_type(8))) short bf16x8;
typedef __attribute__((ext_vector_type(4))) float f32x4;

__device__ __forceinline__ float softplusf(float x){
  return fmaxf(x, 0.f) + log1pf(expf(-fabsf(x)));
}
__device__ __forceinline__ float sigmoidf(float x){
  return 1.f / (1.f + expf(-x));
}
__device__ __forceinline__ unsigned short f2bf(float f){
  __hip_bfloat16 h = __float2bfloat16(f);
  unsigned short u; __builtin_memcpy(&u, &h, 2); return u;
}
__device__ __forceinline__ float bf2f(unsigned short u){
  __hip_bfloat16 h; __builtin_memcpy(&h, &u, 2); return __bfloat162float(h);
}

// ---------------- embedding: a = atom_fea @ W_emb + b_emb ----------------
__global__ void k_embed(const float* __restrict__ af, const float* __restrict__ W,
                        const float* __restrict__ b, float* __restrict__ a){
  __shared__ float row[4][ORIG];
  int base = blockIdx.x * 4;
  for(int t = threadIdx.x; t < 4*ORIG; t += 256){
    row[t/ORIG][t%ORIG] = af[(size_t)(base + t/ORIG)*ORIG + (t%ORIG)];
  }
  __syncthreads();
  int i = base + (threadIdx.x >> 6);
  int j = threadIdx.x & 63;
  const float* r = row[threadIdx.x >> 6];
  float acc = b[j];
  #pragma unroll
  for(int k = 0; k < ORIG; k++) acc = fmaf(r[k], W[k*F + j], acc);
  a[(size_t)i*F + j] = acc;
}

// ---------------- S = X@W[0:64,:] + bias ; P = X@W[64:128,:] (bf16 pairs) --
__global__ void k_spgemm(const float* __restrict__ X, const float* __restrict__ W,
                         const float* __restrict__ bias,
                         float* __restrict__ S, ushort2* __restrict__ P2){
  __shared__ float x[F];
  int i = blockIdx.x;
  int t = threadIdx.x;
  if(t < F) x[t] = X[(size_t)i*F + t];
  __syncthreads();
  if(t < 128){
    float acc = bias[t];
    #pragma unroll
    for(int k = 0; k < F; k++) acc = fmaf(x[k], W[k*128 + t], acc);
    S[(size_t)i*128 + t] = acc;
  } else {
    int c = t - 128;
    float alo = 0.f, ahi = 0.f;
    #pragma unroll
    for(int k = 0; k < F; k++){
      float xv = x[k];
      alo = fmaf(xv, W[(F + k)*128 + c], alo);
      ahi = fmaf(xv, W[(F + k)*128 + 64 + c], ahi);
    }
    ushort2 o; o.x = f2bf(alo); o.y = f2bf(ahi);
    P2[(size_t)i*64 + c] = o;
  }
}

// ------------- W_e -> bf16 MFMA B-fragments, frag-major layout ------------
// frag f = ct*2 + s (ct: col-tile 0..7, s: K-step 0..1)
// webf[(f*64 + lane)*8 + e] = W[128 + k][ct*16 + (lane&15)], k = s*32+(lane>>4)*8+e
__global__ void k_prep_w(const float* __restrict__ W, unsigned short* __restrict__ webf){
  int l = threadIdx.x, lr = l & 15, lg = l >> 4;
  for(int f = 0; f < 16; ++f){
    int ct = f >> 1, s = f & 1;
    unsigned short* dst = webf + ((size_t)f*64 + l)*8;
    #pragma unroll
    for(int e = 0; e < 8; ++e){
      int k = s*32 + lg*8 + e;
      float w = (k < NBR) ? W[(size_t)(128 + k)*128 + ct*16 + lr] : 0.f;
      dst[e] = f2bf(w);
    }
  }
}

// ---------------- unified MFMA pass over (atom, m) rows -------------------
// MODE 0: stats (col sums/sumsq of gated, 128 ch)  -> part[blk*256 + ...]
// MODE 1: apply (BN1 + sig*softplus, sum over m)   -> SUMb + part[blk*128 + ...]
// Block = 1 wave (64 threads), 16 atoms. Row-tile = 16 atoms at fixed m.
template<int MODE>
__global__ __launch_bounds__(64, 2)
void k_pass(const float* __restrict__ S, const ushort2* __restrict__ P2,
            const float* __restrict__ nbr, const int* __restrict__ idx,
            const unsigned short* __restrict__ webf,
            const float* __restrict__ sc1, const float* __restrict__ sh1,
            float* __restrict__ SUMb, float* __restrict__ part){
  int l = threadIdx.x, lr = l & 15, lg = l >> 4;
  int a0 = blockIdx.x * ATB;

  // B fragments (16 x 16B, coalesced)
  bf16x8 Bf[16];
  const bf16x8* wv = (const bf16x8*)webf;
  #pragma unroll
  for(int f = 0; f < 16; ++f) Bf[f] = wv[f*64 + l];

  // exact-f32 self part: SD[ct][r] = S[a0+lg*4+r][ct*16+lr]
  float SD[8][4];
  #pragma unroll
  for(int ct = 0; ct < 8; ++ct)
    #pragma unroll
    for(int r = 0; r < 4; ++r)
      SD[ct][r] = S[(size_t)(a0 + lg*4 + r)*128 + ct*16 + lr];

  __shared__ int six[ATB*M];
  #pragma unroll
  for(int t = 0; t < 3; ++t) six[l + 64*t] = idx[(size_t)a0*M + l + 64*t];
  __syncthreads();

  float c1f[4], h1f[4], c1c[4], h1c[4];
  if(MODE == 1){
    #pragma unroll
    for(int ct = 0; ct < 4; ++ct){
      c1f[ct] = sc1[ct*16 + lr];      h1f[ct] = sh1[ct*16 + lr];
      c1c[ct] = sc1[64 + ct*16 + lr]; h1c[ct] = sh1[64 + ct*16 + lr];
    }
  }

  float sg[8], ssg[8];       // MODE 0
  float sact[4][4];          // MODE 1: [reg(atom)][ct]
  #pragma unroll
  for(int c = 0; c < 8; ++c){ sg[c] = 0.f; ssg[c] = 0.f; }
  #pragma unroll
  for(int r = 0; r < 4; ++r)
    #pragma unroll
    for(int ct = 0; ct < 4; ++ct) sact[r][ct] = 0.f;

  for(int m = 0; m < M; ++m){
    // A fragments: row = a0+lr, k = (lg*8..lg*8+7) / (32+lg*8..), f32->bf16
    const float* nrow = nbr + ((size_t)(a0 + lr)*M + m)*NBR;
    bf16x8 A0v, A1v;
    #pragma unroll
    for(int e = 0; e < 8; ++e) A0v[e] = (short)f2bf(nrow[lg*8 + e]);
    #pragma unroll
    for(int e = 0; e < 8; ++e){
      int k = 32 + lg*8 + e;
      A1v[e] = (k < NBR) ? (short)f2bf(nrow[k]) : (short)0;
    }

    f32x4 D[8];
    #pragma unroll
    for(int ct = 0; ct < 8; ++ct){
      f32x4 z = {0.f, 0.f, 0.f, 0.f};
      z = __builtin_amdgcn_mfma_f32_16x16x32_bf16(A0v, Bf[ct*2 + 0], z, 0, 0, 0);
      z = __builtin_amdgcn_mfma_f32_16x16x32_bf16(A1v, Bf[ct*2 + 1], z, 0, 0, 0);
      D[ct] = z;
    }

    // epilogue: gated = E + S + P[gather]
    #pragma unroll
    for(int r = 0; r < 4; ++r){
      int p = six[(lg*4 + r)*M + m];
      const ushort2* Prow = P2 + (size_t)p*64;
      #pragma unroll
      for(int ct = 0; ct < 4; ++ct){
        ushort2 pv = Prow[ct*16 + lr];
        float gf = D[ct][r]     + SD[ct][r]     + bf2f(pv.x);
        float gc = D[ct + 4][r] + SD[ct + 4][r] + bf2f(pv.y);
        if(MODE == 0){
          sg[ct]     += gf;  ssg[ct]     = fmaf(gf, gf, ssg[ct]);
          sg[ct + 4] += gc;  ssg[ct + 4] = fmaf(gc, gc, ssg[ct + 4]);
        } else {
          gf = fmaf(gf, c1f[ct], h1f[ct]);
          gc = fmaf(gc, c1c[ct], h1c[ct]);
          sact[r][ct] += sigmoidf(gf) * softplusf(gc);
        }
      }
    }
  }

  if(MODE == 0){
    #pragma unroll
    for(int c = 0; c < 8; ++c){
      sg[c]  += __shfl_xor(sg[c], 16, 64);  sg[c]  += __shfl_xor(sg[c], 32, 64);
      ssg[c] += __shfl_xor(ssg[c], 16, 64); ssg[c] += __shfl_xor(ssg[c], 32, 64);
    }
    if(lg == 0){
      float* pb = part + (size_t)blockIdx.x * 256;
      #pragma unroll
      for(int ct = 0; ct < 8; ++ct){
        pb[ct*16 + lr]       = sg[ct];
        pb[128 + ct*16 + lr] = ssg[ct];
      }
    }
  } else {
    float ps[4], pss[4];
    #pragma unroll
    for(int ct = 0; ct < 4; ++ct){
      ps[ct] = 0.f; pss[ct] = 0.f;
      #pragma unroll
      for(int r = 0; r < 4; ++r){
        float v = sact[r][ct];
        SUMb[(size_t)(a0 + lg*4 + r)*64 + ct*16 + lr] = v;
        ps[ct] += v; pss[ct] = fmaf(v, v, pss[ct]);
      }
      ps[ct]  += __shfl_xor(ps[ct], 16, 64);  ps[ct]  += __shfl_xor(ps[ct], 32, 64);
      pss[ct] += __shfl_xor(pss[ct], 16, 64); pss[ct] += __shfl_xor(pss[ct], 32, 64);
    }
    if(lg == 0){
      float* pb = part + (size_t)blockIdx.x * 128;
      #pragma unroll
      for(int ct = 0; ct < 4; ++ct){
        pb[ct*16 + lr]      = ps[ct];
        pb[64 + ct*16 + lr] = pss[ct];
      }
    }
  }
}

// ---------------- generic column reduction of partials --------------------
__global__ void k_reduce(const float* __restrict__ part, int nblocks, int width,
                         float* __restrict__ out){
  int col = blockIdx.x;
  float s = 0.f;
  for(int b = threadIdx.x; b < nblocks; b += 256) s += part[(size_t)b*width + col];
  __shared__ float red[256];
  red[threadIdx.x] = s;
  __syncthreads();
  for(int off = 128; off; off >>= 1){
    if(threadIdx.x < off) red[threadIdx.x] += red[threadIdx.x + off];
    __syncthreads();
  }
  if(threadIdx.x == 0) out[col] = red[0];
}

// ---------------- BN finalize -------------------------------------------
__global__ void k_finalize(const float* __restrict__ red, const float* __restrict__ gamma,
                           const float* __restrict__ beta, float* __restrict__ sc,
                           float* __restrict__ sh, float inv, int nch){
  int j = threadIdx.x;
  if(j < nch){
    float mu  = red[j] * inv;
    float var = fmaxf(red[nch + j] * inv - mu*mu, 0.f);
    float r   = rsqrtf(var + EPS);
    float s   = gamma[j] * r;
    sc[j] = s;
    sh[j] = beta[j] - mu * s;
  }
}

// ---------------- epilogue: Y = softplus(X + BN2(summed)) [+res] ----------
__global__ void k_epi(const float* __restrict__ X, const float* __restrict__ SUMb,
                      const float* __restrict__ sc2, const float* __restrict__ sh2,
                      float* __restrict__ Y, int res){
  int stride = gridDim.x * blockDim.x;
  for(int e = blockIdx.x * blockDim.x + threadIdx.x; e < N*F; e += stride){
    int j = e & 63;
    float x = X[e];
    float t = softplusf(x + fmaf(SUMb[e], sc2[j], sh2[j]));
    Y[e] = res ? softplusf(t + x) : t;
  }
}

// ---------------- segment-mean pool over sorted crystal_id ----------------
__global__ void k_pool(const float* __restrict__ A2, const int* __restrict__ cid,
                       float* __restrict__ POOL){
  int c = blockIdx.x;
  int j = threadIdx.x;
  int lo = 0, hi = N;
  while(lo < hi){ int mid = (lo + hi) >> 1; if(cid[mid] < c) lo = mid + 1; else hi = mid; }
  int s0 = lo;
  lo = s0; hi = N;
  while(lo < hi){ int mid = (lo + hi) >> 1; if(cid[mid] < c + 1) lo = mid + 1; else hi = mid; }
  int s1 = lo;
  float s = 0.f;
  for(int i = s0; i < s1; i++) s += A2[(size_t)i*F + j];
  POOL[c*F + j] = s / fmaxf((float)(s1 - s0), 1.f);
}

// ---------------- head ----------------------------------------------------
__global__ void k_head(const float* __restrict__ POOL, const float* __restrict__ Wfc,
                       const float* __restrict__ bfc, const float* __restrict__ Wout,
                       const float* __restrict__ bout, float* __restrict__ out){
  int c = blockIdx.x;
  int t = threadIdx.x;
  __shared__ float spv[F];
  if(t < F) spv[t] = softplusf(POOL[c*F + t]);
  __syncthreads();
  float h = bfc[t];
  #pragma unroll
  for(int k = 0; k < F; k++) h = fmaf(spv[k], Wfc[k*H + t], h);
  h = softplusf(h);
  float v = h * Wout[t];
  #pragma unroll
  for(int off = 32; off; off >>= 1) v += __shfl_down(v, off, 64);
  __shared__ float red[2];
  if((t & 63) == 0) red[t >> 6] = v;
  __syncthreads();
  if(t == 0) out[c] = red[0] + red[1] + bout[0];
}

} // namespace

extern "C" void kernel_launch(void* const* d_in, const int* in_sizes, int n_in,
                              void* d_out, int out_size, void* d_ws, size_t ws_size,
                              hipStream_t stream){
  const float* atom_fea = (const float*)d_in[0];
  const float* nbr_fea  = (const float*)d_in[1];
  const int*   nbr_idx  = (const int*)d_in[2];
  const int*   cid      = (const int*)d_in[3];
  const float* W_emb = (const float*)d_in[4];
  const float* b_emb = (const float*)d_in[5];
  const float* cW  = (const float*)d_in[6];
  const float* cb  = (const float*)d_in[7];
  const float* cg1 = (const float*)d_in[8];
  const float* cbt1= (const float*)d_in[9];
  const float* cg2 = (const float*)d_in[10];
  const float* cbt2= (const float*)d_in[11];
  const float* rW  = (const float*)d_in[12];
  const float* rb  = (const float*)d_in[13];
  const float* rg1 = (const float*)d_in[14];
  const float* rbt1= (const float*)d_in[15];
  const float* rg2 = (const float*)d_in[16];
  const float* rbt2= (const float*)d_in[17];
  const float* W_fc = (const float*)d_in[18];
  const float* b_fc = (const float*)d_in[19];
  const float* W_out= (const float*)d_in[20];
  const float* b_out= (const float*)d_in[21];
  float* out = (float*)d_out;

  char* ws = (char*)d_ws;
  float*   A0   = (float*)(ws + 0);            // N*64 f32
  float*   A1   = (float*)(ws + 25600000);     // N*64 f32
  float*   SUMb = (float*)(ws + 51200000);     // N*64 f32
  float*   S    = (float*)(ws + 76800000);     // N*128 f32
  ushort2* P2   = (ushort2*)(ws + 128000000);  // N*64 ushort2
  float*   POOL = (float*)(ws + 153600000);    // 2000*64 f32
  float*   SP1  = (float*)(ws + 154200000);    // 6250*256 f32 (6.4MB)
  float*   SP2  = (float*)(ws + 160600000);    // 6250*128 f32 (3.2MB)
  float*   STAT = (float*)(ws + 163800000);    // stats scratch
  unsigned short* WEBf = (unsigned short*)(ws + 163900000); // 16KB frag weights
  float* RED1 = STAT;
  float* RED2 = STAT + 256;
  float* SC1  = STAT + 384;
  float* SH1  = STAT + 512;
  float* SC2  = STAT + 640;
  float* SH2  = STAT + 704;

  k_embed<<<N/4, 256, 0, stream>>>(atom_fea, W_emb, b_emb, A0);

  for(int layer = 0; layer < 2; layer++){
    const float* W   = layer ? rW   : cW;
    const float* bb  = layer ? rb   : cb;
    const float* g1  = layer ? rg1  : cg1;
    const float* bt1 = layer ? rbt1 : cbt1;
    const float* g2  = layer ? rg2  : cg2;
    const float* bt2 = layer ? rbt2 : cbt2;
    const float* X = layer ? A1 : A0;
    float*       Y = layer ? A0 : A1;

    k_spgemm<<<N, 192, 0, stream>>>(X, W, bb, S, P2);
    k_prep_w<<<1, 64, 0, stream>>>(W, WEBf);
    k_pass<0><<<NBLK, 64, 0, stream>>>(S, P2, nbr_fea, nbr_idx, WEBf,
                                       SC1, SH1, nullptr, SP1);
    k_reduce<<<256, 256, 0, stream>>>(SP1, NBLK, 256, RED1);
    k_finalize<<<1, 128, 0, stream>>>(RED1, g1, bt1, SC1, SH1, 1.f/(float)(N*M), 128);
    k_pass<1><<<NBLK, 64, 0, stream>>>(S, P2, nbr_fea, nbr_idx, WEBf,
                                       SC1, SH1, SUMb, SP2);
    k_reduce<<<128, 256, 0, stream>>>(SP2, NBLK, 128, RED2);
    k_finalize<<<1, 128, 0, stream>>>(RED2, g2, bt2, SC2, SH2, 1.f/(float)N, 64);
    k_epi<<<2048, 256, 0, stream>>>(X, SUMb, SC2, SH2, Y, layer);
  }

  k_pool<<<N0, 64, 0, stream>>>(A0, cid, POOL);
  k_head<<<N0, 128, 0, stream>>>(POOL, W_fc, b_fc, W_out, b_out, out);
}

// Round 7
// 1106.843 us; speedup vs baseline: 2.1956x; 1.5849x over previous
//
#include <hip/hip_runtime.h>
#include <hip/hip_bf16.h>

namespace {

constexpr int N    = 100000;
constexpr int M    = 12;
constexpr int ORIG = 92;
constexpr int NBR  = 41;
constexpr int F    = 64;
constexpr int H    = 128;
constexpr int N0   = 2000;
constexpr float EPS = 1e-5f;

constexpr int NBLK2 = N / 32;   // 3125 blocks of 32 atoms (2 tiles x 16)

typedef __attribute__((ext_vector_type(8))) short bf16x8;
typedef __attribute__((ext_vector_type(4))) float f32x4;
typedef float f32x4u __attribute__((ext_vector_type(4), aligned(4)));

__device__ __forceinline__ float u2f(unsigned u){ float f; __builtin_memcpy(&f, &u, 4); return f; }

// fast softplus/sigmoid: v_exp/v_log/v_rcp (~1ulp), plenty under bf16-level threshold
__device__ __forceinline__ float softplusf(float x){
  float t = __expf(-fabsf(x));
  return fmaxf(x, 0.f) + 0.693147180559945f * __log2f(1.f + t);
}
__device__ __forceinline__ float sigmoidf(float x){
  return __fdividef(1.f, 1.f + __expf(-x));
}
__device__ __forceinline__ unsigned short f2bf(float f){
  __hip_bfloat16 h = __float2bfloat16(f);
  unsigned short u; __builtin_memcpy(&u, &h, 2); return u;
}
__device__ __forceinline__ float bf2f(unsigned short u){
  __hip_bfloat16 h; __builtin_memcpy(&h, &u, 2); return __bfloat162float(h);
}
// pack 2 f32 -> 2 bf16 elems of an A-fragment (compiler emits v_cvt_pk_bf16_f32)
__device__ __forceinline__ void cvt2(bf16x8& d, int e, float a, float b){
  __hip_bfloat162 b2 = __float22bfloat162_rn(make_float2(a, b));
  unsigned u; __builtin_memcpy(&u, &b2, 4);
  d[e]   = (short)(u & 0xffffu);
  d[e+1] = (short)(u >> 16);
}

// ---------------- embedding: a = atom_fea @ W_emb + b_emb ----------------
__global__ void k_embed(const float* __restrict__ af, const float* __restrict__ W,
                        const float* __restrict__ b, float* __restrict__ a){
  __shared__ float row[4][ORIG];
  int base = blockIdx.x * 4;
  for(int t = threadIdx.x; t < 4*ORIG; t += 256){
    row[t/ORIG][t%ORIG] = af[(size_t)(base + t/ORIG)*ORIG + (t%ORIG)];
  }
  __syncthreads();
  int i = base + (threadIdx.x >> 6);
  int j = threadIdx.x & 63;
  const float* r = row[threadIdx.x >> 6];
  float acc = b[j];
  #pragma unroll
  for(int k = 0; k < ORIG; k++) acc = fmaf(r[k], W[k*F + j], acc);
  a[(size_t)i*F + j] = acc;
}

// ---------------- S = X@W[0:64,:] + bias ; P = X@W[64:128,:] (bf16 pairs) --
__global__ void k_spgemm(const float* __restrict__ X, const float* __restrict__ W,
                         const float* __restrict__ bias,
                         float* __restrict__ S, ushort2* __restrict__ P2){
  __shared__ float x[F];
  int i = blockIdx.x;
  int t = threadIdx.x;
  if(t < F) x[t] = X[(size_t)i*F + t];
  __syncthreads();
  if(t < 128){
    float acc = bias[t];
    #pragma unroll
    for(int k = 0; k < F; k++) acc = fmaf(x[k], W[k*128 + t], acc);
    S[(size_t)i*128 + t] = acc;
  } else {
    int c = t - 128;
    float alo = 0.f, ahi = 0.f;
    #pragma unroll
    for(int k = 0; k < F; k++){
      float xv = x[k];
      alo = fmaf(xv, W[(F + k)*128 + c], alo);
      ahi = fmaf(xv, W[(F + k)*128 + 64 + c], ahi);
    }
    ushort2 o; o.x = f2bf(alo); o.y = f2bf(ahi);
    P2[(size_t)i*64 + c] = o;
  }
}

// ------------- W_e -> bf16 MFMA B-fragments, frag-major layout ------------
// frag f = ct*2 + s (ct: global col-tile 0..7, s: K-step 0..1)
__global__ void k_prep_w(const float* __restrict__ W, unsigned short* __restrict__ webf){
  int l = threadIdx.x, lr = l & 15, lg = l >> 4;
  for(int f = 0; f < 16; ++f){
    int ct = f >> 1, s = f & 1;
    unsigned short* dst = webf + ((size_t)f*64 + l)*8;
    #pragma unroll
    for(int e = 0; e < 8; ++e){
      int k = s*32 + lg*8 + e;
      float w = (k < NBR) ? W[(size_t)(128 + k)*128 + ct*16 + lr] : 0.f;
      dst[e] = f2bf(w);
    }
  }
}

// ---------------- unified MFMA pass over (atom, m) rows -------------------
// Block = 256 threads = 4 waves = 2 atom-tiles (tw) x 2 col-halves (h).
// Wave (tw,h): 16 atoms, cols {32h..32h+31} (filter) + {64+32h..} (core) —
// interleaved split so each wave holds matched filt/core pairs in-register.
// MODE 0: stats (col sums/sumsq of gated, 128 ch)  -> part[(blk*2+tw)*256]
// MODE 1: apply (BN1 + sig*softplus, sum over m)   -> SUMb + part[(blk*2+tw)*128]
template<int MODE>
__global__ __launch_bounds__(256, 3)
void k_pass2(const float* __restrict__ S, const unsigned* __restrict__ P2u,
             const float* __restrict__ nbr, const int* __restrict__ idx,
             const unsigned short* __restrict__ webf,
             const float* __restrict__ sc1, const float* __restrict__ sh1,
             float* __restrict__ SUMb, float* __restrict__ part){
  const int tid = threadIdx.x;
  const int l = tid & 63, lr = l & 15, lg = l >> 4;
  const int wid = tid >> 6, tw = wid >> 1, h = wid & 1;
  const int a0 = blockIdx.x*32 + tw*16;

  // B fragments: 4 local col-tiles x 2 K-steps (32 VGPR)
  bf16x8 Bf[4][2];
  const bf16x8* wv = (const bf16x8*)webf;
  #pragma unroll
  for(int c = 0; c < 4; ++c){
    int cg = (c < 2) ? (2*h + c) : (4 + 2*h + (c - 2));
    Bf[c][0] = wv[(cg*2 + 0)*64 + l];
    Bf[c][1] = wv[(cg*2 + 1)*64 + l];
  }

  // exact-f32 self part for this wave's cols
  float SD[4][4];
  #pragma unroll
  for(int c = 0; c < 4; ++c){
    int col = (c < 2) ? (h*32 + c*16 + lr) : (64 + h*32 + (c - 2)*16 + lr);
    #pragma unroll
    for(int r = 0; r < 4; ++r)
      SD[c][r] = S[(size_t)(a0 + lg*4 + r)*128 + col];
  }

  __shared__ int six[32*M];
  for(int u = tid; u < 32*M; u += 256) six[u] = idx[(size_t)blockIdx.x*32*M + u];
  __syncthreads();

  float c1f[2], h1f[2], c1c[2], h1c[2];
  if(MODE == 1){
    #pragma unroll
    for(int fc = 0; fc < 2; ++fc){
      int j = h*32 + fc*16 + lr;
      c1f[fc] = sc1[j];      h1f[fc] = sh1[j];
      c1c[fc] = sc1[64 + j]; h1c[fc] = sh1[64 + j];
    }
  }

  float sg[4] = {0,0,0,0}, ssg[4] = {0,0,0,0};
  float sact[4][2];
  #pragma unroll
  for(int r = 0; r < 4; ++r){ sact[r][0] = 0.f; sact[r][1] = 0.f; }

  for(int m = 0; m < M; ++m){
    const float* nrow = nbr + ((size_t)(a0 + lr)*M + m)*NBR;
    bf16x8 A0v, A1v = {0,0,0,0,0,0,0,0};
    {
      f32x4u v0 = *(const f32x4u*)(nrow + lg*8);
      f32x4u v1 = *(const f32x4u*)(nrow + lg*8 + 4);
      cvt2(A0v, 0, v0.x, v0.y); cvt2(A0v, 2, v0.z, v0.w);
      cvt2(A0v, 4, v1.x, v1.y); cvt2(A0v, 6, v1.z, v1.w);
    }
    if(lg == 0){        // k = 32..39
      f32x4u v0 = *(const f32x4u*)(nrow + 32);
      f32x4u v1 = *(const f32x4u*)(nrow + 36);
      cvt2(A1v, 0, v0.x, v0.y); cvt2(A1v, 2, v0.z, v0.w);
      cvt2(A1v, 4, v1.x, v1.y); cvt2(A1v, 6, v1.z, v1.w);
    } else if(lg == 1){ // k = 40 only
      A1v[0] = (short)f2bf(nrow[40]);
    }

    f32x4 D[4];
    #pragma unroll
    for(int c = 0; c < 4; ++c){
      f32x4 z = {0.f,0.f,0.f,0.f};
      z = __builtin_amdgcn_mfma_f32_16x16x32_bf16(A0v, Bf[c][0], z, 0, 0, 0);
      z = __builtin_amdgcn_mfma_f32_16x16x32_bf16(A1v, Bf[c][1], z, 0, 0, 0);
      D[c] = z;
    }

    #pragma unroll
    for(int r = 0; r < 4; ++r){
      int p = six[(tw*16 + lg*4 + r)*M + m];
      const unsigned* Prow = P2u + (size_t)p*64 + h*32 + lr;
      #pragma unroll
      for(int fc = 0; fc < 2; ++fc){
        unsigned pv = Prow[fc*16];          // (P_j, P_{j+64}) bf16 pair
        float gf = D[fc][r]     + SD[fc][r]     + u2f(pv << 16);
        float gc = D[2 + fc][r] + SD[2 + fc][r] + u2f(pv & 0xffff0000u);
        if(MODE == 0){
          sg[fc]     += gf;  ssg[fc]     = fmaf(gf, gf, ssg[fc]);
          sg[2 + fc] += gc;  ssg[2 + fc] = fmaf(gc, gc, ssg[2 + fc]);
        } else {
          float bf_ = fmaf(gf, c1f[fc], h1f[fc]);
          float bc_ = fmaf(gc, c1c[fc], h1c[fc]);
          sact[r][fc] += sigmoidf(bf_) * softplusf(bc_);
        }
      }
    }
  }

  if(MODE == 0){
    #pragma unroll
    for(int c = 0; c < 4; ++c){
      sg[c]  += __shfl_xor(sg[c], 16, 64);  sg[c]  += __shfl_xor(sg[c], 32, 64);
      ssg[c] += __shfl_xor(ssg[c], 16, 64); ssg[c] += __shfl_xor(ssg[c], 32, 64);
    }
    if(lg == 0){
      float* pb = part + ((size_t)blockIdx.x*2 + tw)*256;
      #pragma unroll
      for(int c = 0; c < 4; ++c){
        int col = (c < 2) ? (h*32 + c*16 + lr) : (64 + h*32 + (c - 2)*16 + lr);
        pb[col]       = sg[c];
        pb[128 + col] = ssg[c];
      }
    }
  } else {
    float ps[2] = {0,0}, pss[2] = {0,0};
    #pragma unroll
    for(int fc = 0; fc < 2; ++fc){
      #pragma unroll
      for(int r = 0; r < 4; ++r){
        float v = sact[r][fc];
        SUMb[(size_t)(a0 + lg*4 + r)*64 + h*32 + fc*16 + lr] = v;
        ps[fc] += v; pss[fc] = fmaf(v, v, pss[fc]);
      }
      ps[fc]  += __shfl_xor(ps[fc], 16, 64);  ps[fc]  += __shfl_xor(ps[fc], 32, 64);
      pss[fc] += __shfl_xor(pss[fc], 16, 64); pss[fc] += __shfl_xor(pss[fc], 32, 64);
    }
    if(lg == 0){
      float* pb = part + ((size_t)blockIdx.x*2 + tw)*128;
      #pragma unroll
      for(int fc = 0; fc < 2; ++fc){
        int j = h*32 + fc*16 + lr;
        pb[j]      = ps[fc];
        pb[64 + j] = pss[fc];
      }
    }
  }
}

// ---------------- generic column reduction of partials --------------------
__global__ void k_reduce(const float* __restrict__ part, int nblocks, int width,
                         float* __restrict__ out){
  int col = blockIdx.x;
  float s = 0.f;
  for(int b = threadIdx.x; b < nblocks; b += 256) s += part[(size_t)b*width + col];
  __shared__ float red[256];
  red[threadIdx.x] = s;
  __syncthreads();
  for(int off = 128; off; off >>= 1){
    if(threadIdx.x < off) red[threadIdx.x] += red[threadIdx.x + off];
    __syncthreads();
  }
  if(threadIdx.x == 0) out[col] = red[0];
}

// ---------------- BN finalize -------------------------------------------
__global__ void k_finalize(const float* __restrict__ red, const float* __restrict__ gamma,
                           const float* __restrict__ beta, float* __restrict__ sc,
                           float* __restrict__ sh, float inv, int nch){
  int j = threadIdx.x;
  if(j < nch){
    float mu  = red[j] * inv;
    float var = fmaxf(red[nch + j] * inv - mu*mu, 0.f);
    float r   = rsqrtf(var + EPS);
    float s   = gamma[j] * r;
    sc[j] = s;
    sh[j] = beta[j] - mu * s;
  }
}

// ---------------- epilogue: Y = softplus(X + BN2(summed)) [+res] ----------
__global__ void k_epi(const float* __restrict__ X, const float* __restrict__ SUMb,
                      const float* __restrict__ sc2, const float* __restrict__ sh2,
                      float* __restrict__ Y, int res){
  int stride = gridDim.x * blockDim.x;
  for(int e = blockIdx.x * blockDim.x + threadIdx.x; e < N*F; e += stride){
    int j = e & 63;
    float x = X[e];
    float t = softplusf(x + fmaf(SUMb[e], sc2[j], sh2[j]));
    Y[e] = res ? softplusf(t + x) : t;
  }
}

// ---------------- segment-mean pool over sorted crystal_id ----------------
__global__ void k_pool(const float* __restrict__ A2, const int* __restrict__ cid,
                       float* __restrict__ POOL){
  int c = blockIdx.x;
  int j = threadIdx.x;
  int lo = 0, hi = N;
  while(lo < hi){ int mid = (lo + hi) >> 1; if(cid[mid] < c) lo = mid + 1; else hi = mid; }
  int s0 = lo;
  lo = s0; hi = N;
  while(lo < hi){ int mid = (lo + hi) >> 1; if(cid[mid] < c + 1) lo = mid + 1; else hi = mid; }
  int s1 = lo;
  float s = 0.f;
  for(int i = s0; i < s1; i++) s += A2[(size_t)i*F + j];
  POOL[c*F + j] = s / fmaxf((float)(s1 - s0), 1.f);
}

// ---------------- head ----------------------------------------------------
__global__ void k_head(const float* __restrict__ POOL, const float* __restrict__ Wfc,
                       const float* __restrict__ bfc, const float* __restrict__ Wout,
                       const float* __restrict__ bout, float* __restrict__ out){
  int c = blockIdx.x;
  int t = threadIdx.x;
  __shared__ float spv[F];
  if(t < F) spv[t] = softplusf(POOL[c*F + t]);
  __syncthreads();
  float h = bfc[t];
  #pragma unroll
  for(int k = 0; k < F; k++) h = fmaf(spv[k], Wfc[k*H + t], h);
  h = softplusf(h);
  float v = h * Wout[t];
  #pragma unroll
  for(int off = 32; off; off >>= 1) v += __shfl_down(v, off, 64);
  __shared__ float red[2];
  if((t & 63) == 0) red[t >> 6] = v;
  __syncthreads();
  if(t == 0) out[c] = red[0] + red[1] + bout[0];
}

} // namespace

extern "C" void kernel_launch(void* const* d_in, const int* in_sizes, int n_in,
                              void* d_out, int out_size, void* d_ws, size_t ws_size,
                              hipStream_t stream){
  const float* atom_fea = (const float*)d_in[0];
  const float* nbr_fea  = (const float*)d_in[1];
  const int*   nbr_idx  = (const int*)d_in[2];
  const int*   cid      = (const int*)d_in[3];
  const float* W_emb = (const float*)d_in[4];
  const float* b_emb = (const float*)d_in[5];
  const float* cW  = (const float*)d_in[6];
  const float* cb  = (const float*)d_in[7];
  const float* cg1 = (const float*)d_in[8];
  const float* cbt1= (const float*)d_in[9];
  const float* cg2 = (const float*)d_in[10];
  const float* cbt2= (const float*)d_in[11];
  const float* rW  = (const float*)d_in[12];
  const float* rb  = (const float*)d_in[13];
  const float* rg1 = (const float*)d_in[14];
  const float* rbt1= (const float*)d_in[15];
  const float* rg2 = (const float*)d_in[16];
  const float* rbt2= (const float*)d_in[17];
  const float* W_fc = (const float*)d_in[18];
  const float* b_fc = (const float*)d_in[19];
  const float* W_out= (const float*)d_in[20];
  const float* b_out= (const float*)d_in[21];
  float* out = (float*)d_out;

  char* ws = (char*)d_ws;
  float*   A0   = (float*)(ws + 0);            // N*64 f32
  float*   A1   = (float*)(ws + 25600000);     // N*64 f32
  float*   SUMb = (float*)(ws + 51200000);     // N*64 f32
  float*   S    = (float*)(ws + 76800000);     // N*128 f32
  ushort2* P2   = (ushort2*)(ws + 128000000);  // N*64 ushort2
  float*   POOL = (float*)(ws + 153600000);    // 2000*64 f32
  float*   SP1  = (float*)(ws + 154200000);    // 6250*256 f32 (6.4MB)
  float*   SP2  = (float*)(ws + 160600000);    // 6250*128 f32 (3.2MB)
  float*   STAT = (float*)(ws + 163800000);    // stats scratch
  unsigned short* WEBf = (unsigned short*)(ws + 163900000); // 16KB frag weights
  float* RED1 = STAT;
  float* RED2 = STAT + 256;
  float* SC1  = STAT + 384;
  float* SH1  = STAT + 512;
  float* SC2  = STAT + 640;
  float* SH2  = STAT + 704;

  k_embed<<<N/4, 256, 0, stream>>>(atom_fea, W_emb, b_emb, A0);

  for(int layer = 0; layer < 2; layer++){
    const float* W   = layer ? rW   : cW;
    const float* bb  = layer ? rb   : cb;
    const float* g1  = layer ? rg1  : cg1;
    const float* bt1 = layer ? rbt1 : cbt1;
    const float* g2  = layer ? rg2  : cg2;
    const float* bt2 = layer ? rbt2 : cbt2;
    const float* X = layer ? A1 : A0;
    float*       Y = layer ? A0 : A1;

    k_spgemm<<<N, 192, 0, stream>>>(X, W, bb, S, P2);
    k_prep_w<<<1, 64, 0, stream>>>(W, WEBf);
    k_pass2<0><<<NBLK2, 256, 0, stream>>>(S, (const unsigned*)P2, nbr_fea, nbr_idx,
                                          WEBf, SC1, SH1, nullptr, SP1);
    k_reduce<<<256, 256, 0, stream>>>(SP1, 2*NBLK2, 256, RED1);
    k_finalize<<<1, 128, 0, stream>>>(RED1, g1, bt1, SC1, SH1, 1.f/(float)(N*M), 128);
    k_pass2<1><<<NBLK2, 256, 0, stream>>>(S, (const unsigned*)P2, nbr_fea, nbr_idx,
                                          WEBf, SC1, SH1, SUMb, SP2);
    k_reduce<<<128, 256, 0, stream>>>(SP2, 2*NBLK2, 128, RED2);
    k_finalize<<<1, 128, 0, stream>>>(RED2, g2, bt2, SC2, SH2, 1.f/(float)N, 64);
    k_epi<<<2048, 256, 0, stream>>>(X, SUMb, SC2, SH2, Y, layer);
  }

  k_pool<<<N0, 64, 0, stream>>>(A0, cid, POOL);
  k_head<<<N0, 128, 0, stream>>>(POOL, W_fc, b_fc, W_out, b_out, out);
}

// Round 8
// 717.263 us; speedup vs baseline: 3.3882x; 1.5431x over previous
//
#include <hip/hip_runtime.h>
#include <hip/hip_bf16.h>

namespace {

constexpr int N    = 100000;
constexpr int M    = 12;
constexpr int ORIG = 92;
constexpr int NBR  = 41;
constexpr int F    = 64;
constexpr int H    = 128;
constexpr int N0   = 2000;
constexpr float EPS = 1e-5f;

constexpr int NBLK2 = N / 32;   // 3125 blocks of 32 atoms

typedef __attribute__((ext_vector_type(8))) short bf16x8;
typedef __attribute__((ext_vector_type(4))) float f32x4;
typedef float f32x4u __attribute__((ext_vector_type(4), aligned(4)));

__device__ __forceinline__ float u2f(unsigned u){ float f; __builtin_memcpy(&f, &u, 4); return f; }

// fast softplus/sigmoid: v_exp/v_log/v_rcp (~1ulp)
__device__ __forceinline__ float softplusf(float x){
  float t = __expf(-fabsf(x));
  return fmaxf(x, 0.f) + 0.693147180559945f * __log2f(1.f + t);
}
__device__ __forceinline__ float sigmoidf(float x){
  return __fdividef(1.f, 1.f + __expf(-x));
}
__device__ __forceinline__ unsigned short f2bf(float f){
  __hip_bfloat16 h = __float2bfloat16(f);
  unsigned short u; __builtin_memcpy(&u, &h, 2); return u;
}
// pack 2 f32 -> u32 of 2 bf16 (lo in low 16)
__device__ __forceinline__ unsigned packbf2(float lo, float hi){
  __hip_bfloat162 b2 = __float22bfloat162_rn(make_float2(lo, hi));
  unsigned u; __builtin_memcpy(&u, &b2, 4); return u;
}
__device__ __forceinline__ void cvt2(bf16x8& d, int e, float a, float b){
  unsigned u = packbf2(a, b);
  d[e]   = (short)(u & 0xffffu);
  d[e+1] = (short)(u >> 16);
}

// ---------------- embedding: a = atom_fea @ W_emb + b_emb ----------------
__global__ void k_embed(const float* __restrict__ af, const float* __restrict__ W,
                        const float* __restrict__ b, float* __restrict__ a){
  __shared__ float row[4][ORIG];
  int base = blockIdx.x * 4;
  for(int t = threadIdx.x; t < 4*ORIG; t += 256){
    row[t/ORIG][t%ORIG] = af[(size_t)(base + t/ORIG)*ORIG + (t%ORIG)];
  }
  __syncthreads();
  int i = base + (threadIdx.x >> 6);
  int j = threadIdx.x & 63;
  const float* r = row[threadIdx.x >> 6];
  float acc = b[j];
  #pragma unroll
  for(int k = 0; k < ORIG; k++) acc = fmaf(r[k], W[k*F + j], acc);
  a[(size_t)i*F + j] = acc;
}

// -------- W -> bf16 MFMA B-fragments (E-panel and S/P-panel) --------------
// block b < 16: E-frag b (ct=b>>1, kstep=b&1) over W rows 128..168 (K=41 pad 64)
// block b >= 16: SP-frag f=b-16 (ct=f>>1, ks=f&1) over virtual B[k][c]:
//   c<128 -> W[k][c] (self), c>=128 -> W[64+k][c-128] (gather), k in 0..63
__global__ void k_prep(const float* __restrict__ W,
                       unsigned short* __restrict__ webf,
                       unsigned short* __restrict__ wspf){
  int b = blockIdx.x;
  int l = threadIdx.x, lr = l & 15, lg = l >> 4;
  if(b < 16){
    int ct = b >> 1, s = b & 1;
    unsigned short* dst = webf + ((size_t)b*64 + l)*8;
    #pragma unroll
    for(int e = 0; e < 8; ++e){
      int k = s*32 + lg*8 + e;
      float w = (k < NBR) ? W[(size_t)(128 + k)*128 + ct*16 + lr] : 0.f;
      dst[e] = f2bf(w);
    }
  } else {
    int f = b - 16;
    int ct = f >> 1, ks = f & 1;
    int col = ct*16 + lr;
    unsigned short* dst = wspf + ((size_t)f*64 + l)*8;
    #pragma unroll
    for(int e = 0; e < 8; ++e){
      int k = ks*32 + lg*8 + e;
      float w = (col < 128) ? W[(size_t)k*128 + col]
                            : W[(size_t)(64 + k)*128 + (col - 128)];
      dst[e] = f2bf(w);
    }
  }
}

// ---------------- S/P GEMM via MFMA: (N x 64) @ (64 x 256) ----------------
// Block = 4 waves, 32 atoms (2 atom-tiles). Wave w: S col-tiles {2w,2w+1}
// (+bias, f32 store) and P col-tiles {8+w,12+w} packed to bf16 pairs.
__global__ __launch_bounds__(256, 3)
void k_spmm(const float* __restrict__ X, const unsigned short* __restrict__ wspf,
            const float* __restrict__ bias,
            float* __restrict__ S, unsigned* __restrict__ P2u){
  const int tid = threadIdx.x;
  const int l = tid & 63, lr = l & 15, lg = l >> 4;
  const int w = tid >> 6;
  const int a0 = blockIdx.x * 32;
  const bf16x8* wv = (const bf16x8*)wspf;

  bf16x8 BS[2][2], BPl[2], BPh[2];
  #pragma unroll
  for(int c = 0; c < 2; ++c)
    #pragma unroll
    for(int ks = 0; ks < 2; ++ks)
      BS[c][ks] = wv[((2*w + c)*2 + ks)*64 + l];
  #pragma unroll
  for(int ks = 0; ks < 2; ++ks){
    BPl[ks] = wv[((8 + w)*2 + ks)*64 + l];
    BPh[ks] = wv[((12 + w)*2 + ks)*64 + l];
  }

  bf16x8 A[2][2];
  #pragma unroll
  for(int t = 0; t < 2; ++t){
    const float* xr = X + (size_t)(a0 + t*16 + lr)*64;
    #pragma unroll
    for(int ks = 0; ks < 2; ++ks){
      f32x4u v0 = *(const f32x4u*)(xr + ks*32 + lg*8);
      f32x4u v1 = *(const f32x4u*)(xr + ks*32 + lg*8 + 4);
      cvt2(A[t][ks], 0, v0.x, v0.y); cvt2(A[t][ks], 2, v0.z, v0.w);
      cvt2(A[t][ks], 4, v1.x, v1.y); cvt2(A[t][ks], 6, v1.z, v1.w);
    }
  }

  f32x4 DS[2][2], DPl[2], DPh[2];
  #pragma unroll
  for(int t = 0; t < 2; ++t){
    #pragma unroll
    for(int c = 0; c < 2; ++c){
      f32x4 z = {0.f,0.f,0.f,0.f};
      z = __builtin_amdgcn_mfma_f32_16x16x32_bf16(A[t][0], BS[c][0], z, 0, 0, 0);
      z = __builtin_amdgcn_mfma_f32_16x16x32_bf16(A[t][1], BS[c][1], z, 0, 0, 0);
      DS[t][c] = z;
    }
    f32x4 zl = {0.f,0.f,0.f,0.f}, zh = {0.f,0.f,0.f,0.f};
    zl = __builtin_amdgcn_mfma_f32_16x16x32_bf16(A[t][0], BPl[0], zl, 0, 0, 0);
    zl = __builtin_amdgcn_mfma_f32_16x16x32_bf16(A[t][1], BPl[1], zl, 0, 0, 0);
    zh = __builtin_amdgcn_mfma_f32_16x16x32_bf16(A[t][0], BPh[0], zh, 0, 0, 0);
    zh = __builtin_amdgcn_mfma_f32_16x16x32_bf16(A[t][1], BPh[1], zh, 0, 0, 0);
    DPl[t] = zl; DPh[t] = zh;
  }

  float bS[2];
  #pragma unroll
  for(int c = 0; c < 2; ++c) bS[c] = bias[(2*w + c)*16 + lr];

  #pragma unroll
  for(int t = 0; t < 2; ++t){
    #pragma unroll
    for(int r = 0; r < 4; ++r){
      size_t row = a0 + t*16 + lg*4 + r;
      #pragma unroll
      for(int c = 0; c < 2; ++c)
        S[row*128 + (2*w + c)*16 + lr] = DS[t][c][r] + bS[c];
      P2u[row*64 + w*16 + lr] = packbf2(DPl[t][r], DPh[t][r]);
    }
  }
}

// ---------------- unified MFMA pass over (atom, m) rows -------------------
// Block = 256 threads = 4 waves = 2 atom-tiles (tw) x 2 col-halves (h).
template<int MODE>
__global__ __launch_bounds__(256, 3)
void k_pass2(const float* __restrict__ S, const unsigned* __restrict__ P2u,
             const float* __restrict__ nbr, const int* __restrict__ idx,
             const unsigned short* __restrict__ webf,
             const float* __restrict__ sc1, const float* __restrict__ sh1,
             float* __restrict__ SUMb, float* __restrict__ part){
  const int tid = threadIdx.x;
  const int l = tid & 63, lr = l & 15, lg = l >> 4;
  const int wid = tid >> 6, tw = wid >> 1, h = wid & 1;
  const int a0 = blockIdx.x*32 + tw*16;

  bf16x8 Bf[4][2];
  const bf16x8* wv = (const bf16x8*)webf;
  #pragma unroll
  for(int c = 0; c < 4; ++c){
    int cg = (c < 2) ? (2*h + c) : (4 + 2*h + (c - 2));
    Bf[c][0] = wv[(cg*2 + 0)*64 + l];
    Bf[c][1] = wv[(cg*2 + 1)*64 + l];
  }

  float SD[4][4];
  #pragma unroll
  for(int c = 0; c < 4; ++c){
    int col = (c < 2) ? (h*32 + c*16 + lr) : (64 + h*32 + (c - 2)*16 + lr);
    #pragma unroll
    for(int r = 0; r < 4; ++r)
      SD[c][r] = S[(size_t)(a0 + lg*4 + r)*128 + col];
  }

  __shared__ int six[32*M];
  for(int u = tid; u < 32*M; u += 256) six[u] = idx[(size_t)blockIdx.x*32*M + u];
  __syncthreads();

  float c1f[2], h1f[2], c1c[2], h1c[2];
  if(MODE == 1){
    #pragma unroll
    for(int fc = 0; fc < 2; ++fc){
      int j = h*32 + fc*16 + lr;
      c1f[fc] = sc1[j];      h1f[fc] = sh1[j];
      c1c[fc] = sc1[64 + j]; h1c[fc] = sh1[64 + j];
    }
  }

  float sg[4] = {0,0,0,0}, ssg[4] = {0,0,0,0};
  float sact[4][2];
  #pragma unroll
  for(int r = 0; r < 4; ++r){ sact[r][0] = 0.f; sact[r][1] = 0.f; }

  for(int m = 0; m < M; ++m){
    const float* nrow = nbr + ((size_t)(a0 + lr)*M + m)*NBR;
    bf16x8 A0v, A1v = {0,0,0,0,0,0,0,0};
    {
      f32x4u v0 = *(const f32x4u*)(nrow + lg*8);
      f32x4u v1 = *(const f32x4u*)(nrow + lg*8 + 4);
      cvt2(A0v, 0, v0.x, v0.y); cvt2(A0v, 2, v0.z, v0.w);
      cvt2(A0v, 4, v1.x, v1.y); cvt2(A0v, 6, v1.z, v1.w);
    }
    if(lg == 0){
      f32x4u v0 = *(const f32x4u*)(nrow + 32);
      f32x4u v1 = *(const f32x4u*)(nrow + 36);
      cvt2(A1v, 0, v0.x, v0.y); cvt2(A1v, 2, v0.z, v0.w);
      cvt2(A1v, 4, v1.x, v1.y); cvt2(A1v, 6, v1.z, v1.w);
    } else if(lg == 1){
      A1v[0] = (short)f2bf(nrow[40]);
    }

    f32x4 D[4];
    #pragma unroll
    for(int c = 0; c < 4; ++c){
      f32x4 z = {0.f,0.f,0.f,0.f};
      z = __builtin_amdgcn_mfma_f32_16x16x32_bf16(A0v, Bf[c][0], z, 0, 0, 0);
      z = __builtin_amdgcn_mfma_f32_16x16x32_bf16(A1v, Bf[c][1], z, 0, 0, 0);
      D[c] = z;
    }

    #pragma unroll
    for(int r = 0; r < 4; ++r){
      int p = six[(tw*16 + lg*4 + r)*M + m];
      const unsigned* Prow = P2u + (size_t)p*64 + h*32 + lr;
      #pragma unroll
      for(int fc = 0; fc < 2; ++fc){
        unsigned pv = Prow[fc*16];
        float gf = D[fc][r]     + SD[fc][r]     + u2f(pv << 16);
        float gc = D[2 + fc][r] + SD[2 + fc][r] + u2f(pv & 0xffff0000u);
        if(MODE == 0){
          sg[fc]     += gf;  ssg[fc]     = fmaf(gf, gf, ssg[fc]);
          sg[2 + fc] += gc;  ssg[2 + fc] = fmaf(gc, gc, ssg[2 + fc]);
        } else {
          float bf_ = fmaf(gf, c1f[fc], h1f[fc]);
          float bc_ = fmaf(gc, c1c[fc], h1c[fc]);
          sact[r][fc] += sigmoidf(bf_) * softplusf(bc_);
        }
      }
    }
  }

  if(MODE == 0){
    #pragma unroll
    for(int c = 0; c < 4; ++c){
      sg[c]  += __shfl_xor(sg[c], 16, 64);  sg[c]  += __shfl_xor(sg[c], 32, 64);
      ssg[c] += __shfl_xor(ssg[c], 16, 64); ssg[c] += __shfl_xor(ssg[c], 32, 64);
    }
    if(lg == 0){
      float* pb = part + ((size_t)blockIdx.x*2 + tw)*256;
      #pragma unroll
      for(int c = 0; c < 4; ++c){
        int col = (c < 2) ? (h*32 + c*16 + lr) : (64 + h*32 + (c - 2)*16 + lr);
        pb[col]       = sg[c];
        pb[128 + col] = ssg[c];
      }
    }
  } else {
    float ps[2] = {0,0}, pss[2] = {0,0};
    #pragma unroll
    for(int fc = 0; fc < 2; ++fc){
      #pragma unroll
      for(int r = 0; r < 4; ++r){
        float v = sact[r][fc];
        SUMb[(size_t)(a0 + lg*4 + r)*64 + h*32 + fc*16 + lr] = v;
        ps[fc] += v; pss[fc] = fmaf(v, v, pss[fc]);
      }
      ps[fc]  += __shfl_xor(ps[fc], 16, 64);  ps[fc]  += __shfl_xor(ps[fc], 32, 64);
      pss[fc] += __shfl_xor(pss[fc], 16, 64); pss[fc] += __shfl_xor(pss[fc], 32, 64);
    }
    if(lg == 0){
      float* pb = part + ((size_t)blockIdx.x*2 + tw)*128;
      #pragma unroll
      for(int fc = 0; fc < 2; ++fc){
        int j = h*32 + fc*16 + lr;
        pb[j]      = ps[fc];
        pb[64 + j] = pss[fc];
      }
    }
  }
}

// ---------------- generic column reduction of partials --------------------
__global__ void k_reduce(const float* __restrict__ part, int nblocks, int width,
                         float* __restrict__ out){
  int col = blockIdx.x;
  float s = 0.f;
  for(int b = threadIdx.x; b < nblocks; b += 256) s += part[(size_t)b*width + col];
  __shared__ float red[256];
  red[threadIdx.x] = s;
  __syncthreads();
  for(int off = 128; off; off >>= 1){
    if(threadIdx.x < off) red[threadIdx.x] += red[threadIdx.x + off];
    __syncthreads();
  }
  if(threadIdx.x == 0) out[col] = red[0];
}

// ---------------- BN finalize -------------------------------------------
__global__ void k_finalize(const float* __restrict__ red, const float* __restrict__ gamma,
                           const float* __restrict__ beta, float* __restrict__ sc,
                           float* __restrict__ sh, float inv, int nch){
  int j = threadIdx.x;
  if(j < nch){
    float mu  = red[j] * inv;
    float var = fmaxf(red[nch + j] * inv - mu*mu, 0.f);
    float r   = rsqrtf(var + EPS);
    float s   = gamma[j] * r;
    sc[j] = s;
    sh[j] = beta[j] - mu * s;
  }
}

// ---------------- epilogue: Y = softplus(X + BN2(summed)) [+res] ----------
__global__ void k_epi(const float* __restrict__ X, const float* __restrict__ SUMb,
                      const float* __restrict__ sc2, const float* __restrict__ sh2,
                      float* __restrict__ Y, int res){
  int stride = gridDim.x * blockDim.x;
  for(int e = blockIdx.x * blockDim.x + threadIdx.x; e < N*F; e += stride){
    int j = e & 63;
    float x = X[e];
    float t = softplusf(x + fmaf(SUMb[e], sc2[j], sh2[j]));
    Y[e] = res ? softplusf(t + x) : t;
  }
}

// ---------------- segment-mean pool over sorted crystal_id ----------------
__global__ void k_pool(const float* __restrict__ A2, const int* __restrict__ cid,
                       float* __restrict__ POOL){
  int c = blockIdx.x;
  int j = threadIdx.x;
  int lo = 0, hi = N;
  while(lo < hi){ int mid = (lo + hi) >> 1; if(cid[mid] < c) lo = mid + 1; else hi = mid; }
  int s0 = lo;
  lo = s0; hi = N;
  while(lo < hi){ int mid = (lo + hi) >> 1; if(cid[mid] < c + 1) lo = mid + 1; else hi = mid; }
  int s1 = lo;
  float s = 0.f;
  for(int i = s0; i < s1; i++) s += A2[(size_t)i*F + j];
  POOL[c*F + j] = s / fmaxf((float)(s1 - s0), 1.f);
}

// ---------------- head ----------------------------------------------------
__global__ void k_head(const float* __restrict__ POOL, const float* __restrict__ Wfc,
                       const float* __restrict__ bfc, const float* __restrict__ Wout,
                       const float* __restrict__ bout, float* __restrict__ out){
  int c = blockIdx.x;
  int t = threadIdx.x;
  __shared__ float spv[F];
  if(t < F) spv[t] = softplusf(POOL[c*F + t]);
  __syncthreads();
  float h = bfc[t];
  #pragma unroll
  for(int k = 0; k < F; k++) h = fmaf(spv[k], Wfc[k*H + t], h);
  h = softplusf(h);
  float v = h * Wout[t];
  #pragma unroll
  for(int off = 32; off; off >>= 1) v += __shfl_down(v, off, 64);
  __shared__ float red[2];
  if((t & 63) == 0) red[t >> 6] = v;
  __syncthreads();
  if(t == 0) out[c] = red[0] + red[1] + bout[0];
}

} // namespace

extern "C" void kernel_launch(void* const* d_in, const int* in_sizes, int n_in,
                              void* d_out, int out_size, void* d_ws, size_t ws_size,
                              hipStream_t stream){
  const float* atom_fea = (const float*)d_in[0];
  const float* nbr_fea  = (const float*)d_in[1];
  const int*   nbr_idx  = (const int*)d_in[2];
  const int*   cid      = (const int*)d_in[3];
  const float* W_emb = (const float*)d_in[4];
  const float* b_emb = (const float*)d_in[5];
  const float* cW  = (const float*)d_in[6];
  const float* cb  = (const float*)d_in[7];
  const float* cg1 = (const float*)d_in[8];
  const float* cbt1= (const float*)d_in[9];
  const float* cg2 = (const float*)d_in[10];
  const float* cbt2= (const float*)d_in[11];
  const float* rW  = (const float*)d_in[12];
  const float* rb  = (const float*)d_in[13];
  const float* rg1 = (const float*)d_in[14];
  const float* rbt1= (const float*)d_in[15];
  const float* rg2 = (const float*)d_in[16];
  const float* rbt2= (const float*)d_in[17];
  const float* W_fc = (const float*)d_in[18];
  const float* b_fc = (const float*)d_in[19];
  const float* W_out= (const float*)d_in[20];
  const float* b_out= (const float*)d_in[21];
  float* out = (float*)d_out;

  char* ws = (char*)d_ws;
  float*   A0   = (float*)(ws + 0);            // N*64 f32
  float*   A1   = (float*)(ws + 25600000);     // N*64 f32
  float*   SUMb = (float*)(ws + 51200000);     // N*64 f32
  float*   S    = (float*)(ws + 76800000);     // N*128 f32
  unsigned* P2u = (unsigned*)(ws + 128000000); // N*64 u32 (bf16 pairs)
  float*   POOL = (float*)(ws + 153600000);    // 2000*64 f32
  float*   SP1  = (float*)(ws + 154200000);    // 6250*256 f32
  float*   SP2  = (float*)(ws + 160600000);    // 6250*128 f32
  float*   STAT = (float*)(ws + 163800000);    // stats scratch
  unsigned short* WEBf = (unsigned short*)(ws + 163900000); // 16KB E-frags
  unsigned short* WSPf = (unsigned short*)(ws + 163932000); // 32KB SP-frags
  float* RED1 = STAT;
  float* RED2 = STAT + 256;
  float* SC1  = STAT + 384;
  float* SH1  = STAT + 512;
  float* SC2  = STAT + 640;
  float* SH2  = STAT + 704;

  k_embed<<<N/4, 256, 0, stream>>>(atom_fea, W_emb, b_emb, A0);

  for(int layer = 0; layer < 2; layer++){
    const float* W   = layer ? rW   : cW;
    const float* bb  = layer ? rb   : cb;
    const float* g1  = layer ? rg1  : cg1;
    const float* bt1 = layer ? rbt1 : cbt1;
    const float* g2  = layer ? rg2  : cg2;
    const float* bt2 = layer ? rbt2 : cbt2;
    const float* X = layer ? A1 : A0;
    float*       Y = layer ? A0 : A1;

    k_prep<<<48, 64, 0, stream>>>(W, WEBf, WSPf);
    k_spmm<<<NBLK2, 256, 0, stream>>>(X, WSPf, bb, S, P2u);
    k_pass2<0><<<NBLK2, 256, 0, stream>>>(S, P2u, nbr_fea, nbr_idx,
                                          WEBf, SC1, SH1, nullptr, SP1);
    k_reduce<<<256, 256, 0, stream>>>(SP1, 2*NBLK2, 256, RED1);
    k_finalize<<<1, 128, 0, stream>>>(RED1, g1, bt1, SC1, SH1, 1.f/(float)(N*M), 128);
    k_pass2<1><<<NBLK2, 256, 0, stream>>>(S, P2u, nbr_fea, nbr_idx,
                                          WEBf, SC1, SH1, SUMb, SP2);
    k_reduce<<<128, 256, 0, stream>>>(SP2, 2*NBLK2, 128, RED2);
    k_finalize<<<1, 128, 0, stream>>>(RED2, g2, bt2, SC2, SH2, 1.f/(float)N, 64);
    k_epi<<<2048, 256, 0, stream>>>(X, SUMb, SC2, SH2, Y, layer);
  }

  k_pool<<<N0, 64, 0, stream>>>(A0, cid, POOL);
  k_head<<<N0, 128, 0, stream>>>(POOL, W_fc, b_fc, W_out, b_out, out);
}